// Round 4
// baseline (79.344 us; speedup 1.0000x reference)
//
#include <hip/hip_runtime.h>
#include <math.h>

// S4D kernel materialization:
//   dt = exp(inv_dt[h]);  A = -exp(A_real) + i*A_imag;  dtA = dt*A
//   Cm = (B*C) * (exp(dtA)-1)/A          (complex, per h,n)
//   K[h,l] = 2 * Re( sum_n Cm[h,n] * exp(dtA[h,n] * l) )
//
// H=1024, N=64, CH=1, L=2048. Output (1,H,L) float32 = 8 MB.
//
// R4: occupancy fix. R3 ran 2 waves/SIMD (latency-bound, ~3x off ideal issue).
// Now: one h per block, TPB=256 = 4 waves. Wave w handles n in [16w,16w+16);
// lane owns l = lane + 64*j, j=0..31 (J=32 halves trans setup vs J=16).
// -> 4096 waves = 4 waves/SIMD, ideal issue ~6.3 us, setup ~19%.
// Second-order real recurrence per (n, lane): x_{j+1}=2Re(W)x_j - |W|^2 x_{j-1},
// W = exp(dtA*64). 3 VALU ops per (n,l). Cross-wave n-reduction through LDS
// partials [wave][lane][j] padded to stride 33 (<=2-way bank alias = free).

#define HH 1024
#define NN 64
#define TPB 256
#define NWAVE 4
#define NPW 16         // n per wave
#define STEP 64        // lanes per wave = l-stride per recurrence step
#define LPT 32         // 2048 / 64
#define RJ 33          // padded j-stride in reduce buffer
#define LOG2E  1.4426950408889634f
#define INV2PI 0.15915494309189535f

__global__ __launch_bounds__(TPB, 4) void s4d_recur3_kernel(
    const float* __restrict__ A_real,
    const float* __restrict__ A_imag,
    const float* __restrict__ B,
    const float* __restrict__ C,
    const float* __restrict__ inv_dt,
    float* __restrict__ out,
    int L)
{
    __shared__ float4 pA[NN];              // (dre*log2e, dim/2pi, 2*Cm.re, 2*Cm.im)
    __shared__ float4 pW[NN];              // (Wr, Wi, 2*Wr, |W|^2)
    __shared__ float red[NWAVE * STEP * RJ];  // partials, ~33.8 KB

    const int h    = blockIdx.x;
    const int t    = threadIdx.x;
    const int lane = t & 63;
    const int w    = t >> 6;

    if (t < NN) {
        const int n  = t;
        const int hn = h * NN + n;
        float Ar = A_real[hn];
        float Ai = A_imag[hn];
        float dt = expf(inv_dt[h]);          // rate = 1.0
        float are = -expf(Ar);               // Re(A) = -exp(A_real)
        float dre = dt * are;                // Re(dtA)  (<= 0)
        float dim = dt * Ai;                 // Im(dtA)
        // exp(dtA) - 1
        float er = expf(dre);
        float s, c;
        sincosf(dim, &s, &c);
        float em1r = er * c - 1.0f;
        float em1i = er * s;
        // (exp(dtA)-1)/A  via conj(A)/|A|^2
        float inv = 1.0f / (are * are + Ai * Ai);
        float zr = (em1r * are + em1i * Ai) * inv;
        float zi = (em1i * are - em1r * Ai) * inv;
        // Bc * Cc
        float br = B[2 * hn],  bi = B[2 * hn + 1];
        float Cr = C[2 * hn],  Ci = C[2 * hn + 1];
        float bcr = br * Cr - bi * Ci;
        float bci = br * Ci + bi * Cr;
        // Cm = (Bc*Cc) * z, fold in the final 2x
        float cmr = bcr * zr - bci * zi;
        float cmi = bcr * zi + bci * zr;

        float dreL = dre * LOG2E;
        float dimR = dim * INV2PI;
        // W = exp(dtA * STEP)
        float we = exp2f(dreL * (float)STEP);
        float wx = dimR * (float)STEP;
        float wf = wx - floorf(wx);
        float Wc = __builtin_amdgcn_cosf(wf);
        float Ws = __builtin_amdgcn_sinf(wf);
        float Wr = we * Wc, Wi = we * Ws;
        pA[n] = make_float4(dreL, dimR, 2.0f * cmr, 2.0f * cmi);
        pW[n] = make_float4(Wr, Wi, 2.0f * Wr, Wr * Wr + Wi * Wi);
    }
    __syncthreads();

    float acc[LPT];
#pragma unroll
    for (int j = 0; j < LPT; ++j) acc[j] = 0.0f;

    const float tf = (float)lane;
    const int n0 = w * NPW;

    for (int g = 0; g < NPW; g += 4) {
        float xp[4], xc[4], aa[4], bb[4];
#pragma unroll
        for (int k = 0; k < 4; ++k) {
            const float4 p = pA[n0 + g + k];   // wave-uniform -> LDS broadcast
            const float4 ww = pW[n0 + g + k];
            // z0 = 2*Cm * exp(dtA * lane)
            float e = __builtin_amdgcn_exp2f(p.x * tf);
            float x = p.y * tf;
            float f = x - floorf(x);
            float c = __builtin_amdgcn_cosf(f);
            float s = __builtin_amdgcn_sinf(f);
            float er = e * c, ei = e * s;
            float sr = p.z * er - p.w * ei;   // x0 = Re(z0)
            float si = p.z * ei + p.w * er;
            xp[k] = sr;
            xc[k] = sr * ww.x - si * ww.y;    // x1 = Re(z0 * W)
            aa[k] = ww.z;                     // 2*Re(W)
            bb[k] = ww.w;                     // |W|^2
        }
        acc[0] += (xp[0] + xp[1]) + (xp[2] + xp[3]);
#pragma unroll
        for (int j = 1; j < LPT; ++j) {
#pragma unroll
            for (int k = 0; k < 4; ++k) {
                acc[j] += xc[k];
                float xn = fmaf(aa[k], xc[k], -bb[k] * xp[k]);
                xp[k] = xc[k];
                xc[k] = xn;
            }
        }
    }

    // stash this wave's 32 partials (contiguous j -> b128 writes; lane stride
    // RJ=33 floats keeps bank aliasing <=2-way)
    {
        float* dst = &red[(w * STEP + lane) * RJ];
#pragma unroll
        for (int j = 0; j < LPT; ++j) dst[j] = acc[j];
    }
    __syncthreads();

    // sum the 4 wave-partials; 8 outputs per thread, coalesced stores
#pragma unroll
    for (int r = 0; r < 8; ++r) {
        int p = t + TPB * r;          // 0..2047
        int j  = p >> 6;
        int l2 = p & 63;
        float sum = 0.0f;
#pragma unroll
        for (int v = 0; v < NWAVE; ++v)
            sum += red[(v * STEP + l2) * RJ + j];
        out[h * L + p] = sum;
    }
}

extern "C" void kernel_launch(void* const* d_in, const int* in_sizes, int n_in,
                              void* d_out, int out_size, void* d_ws, size_t ws_size,
                              hipStream_t stream) {
    const float* A_real = (const float*)d_in[0];
    const float* A_imag = (const float*)d_in[1];
    const float* B      = (const float*)d_in[2];
    const float* C      = (const float*)d_in[3];
    const float* inv_dt = (const float*)d_in[4];
    int L = out_size / HH;   // 2048

    s4d_recur3_kernel<<<HH, TPB, 0, stream>>>(A_real, A_imag, B, C, inv_dt,
                                              (float*)d_out, L);
}